// Round 7
// baseline (131.505 us; speedup 1.0000x reference)
//
#include <hip/hip_runtime.h>
#include <hip/hip_bf16.h>

#define WW 20
#define NW 8192         // 64*128 words
#define VOCAB 256
#define EE 64
#define HH 256
#define K3 768          // 3*HH
#define UNIT 2304       // ushorts per vocab unit (P5) = 4608 B

typedef short bf16x8 __attribute__((ext_vector_type(8)));
typedef float f32x4  __attribute__((ext_vector_type(4)));

__device__ __forceinline__ ushort f2bs(float x) {
    __hip_bfloat16 h = __float2bfloat16(x);
    union { __hip_bfloat16 h; ushort u; } c; c.h = h; return c.u;
}
__device__ __forceinline__ float blo(unsigned u) {
    union { unsigned i; float f; } c; c.i = u << 16; return c.f;
}
__device__ __forceinline__ float bhi(unsigned u) {
    union { unsigned i; float f; } c; c.i = u & 0xffff0000u; return c.f;
}

// sliding-window update for one h given this char's 9 bf16 taps.
// j compile-time (fully unrolled caller) so %3/%5 indices and guards fold.
// R17 lesson: no f32x2 packing (VGPR 220 > 128 cliff, halved occupancy).
#define STEP(j, qq, t8v, a3, a5, mm1, mm3, mm5) {                        \
    float t0 = blo((qq).x), t1 = bhi((qq).x);                            \
    float t2 = blo((qq).y), t3 = bhi((qq).y);                            \
    float t4 = blo((qq).z), t5 = bhi((qq).z);                            \
    float t6 = blo((qq).w), t7 = bhi((qq).w);                            \
    mm1 = fmaxf(mm1, t0);                                                \
    if ((j) + 1 < WW) a3[((j)+1)%3] = t1;                                \
    a3[(j)%3] += t2;                                                     \
    if ((j) >= 1) { a3[((j)-1)%3] += t3;                                 \
                    mm3 = fmaxf(mm3, a3[((j)-1)%3]); }                   \
    if ((j) + 2 < WW) a5[((j)+2)%5] = t4;                                \
    if ((j) + 1 < WW) a5[((j)+1)%5] += t5;                               \
    a5[(j)%5] += t6;                                                     \
    if ((j) >= 1) a5[((j)-1)%5] += t7;                                   \
    if ((j) >= 2) { a5[((j)-2)%5] += (t8v);                              \
                    mm5 = fmaxf(mm5, a5[((j)-2)%5]); }                   \
}

// ---------------------------------------------------------------------------
// P5 layout (per vocab v, 2304 ushorts = 4608 B): 32 slices s of 144 B:
//   [hl 0..7][taps 0..7] (8 x 16 B rows), then [tap8 for hl 0..7] (16 B).
// bf16 kept deliberately (R12: f32 table doubled traffic + conflicts).
// R14 lesson: keep the wTp round-trip (fused divergent gather cost +6.6us).
// R18 lesson: tap8 must stay in LDS (global scatter = 335 MB L2 traffic).
// ---------------------------------------------------------------------------

// K0: prep. blocks 0..575: wTp[e][j] f32 (P5 column order);
//     blocks 576..767: lw f32 -> bf16;
//     blocks 768..1407: csb[i] = chars[i]*144 (pre-scaled byte offsets,
//     removes the *144 from conv's hot loop).
__global__ __launch_bounds__(256) void prep(
        const int* __restrict__ chars,
        const float* __restrict__ w1,
        const float* __restrict__ w3,
        const float* __restrict__ w5,
        const float* __restrict__ lw,
        float* __restrict__ wTp,
        ushort* __restrict__ lwb,
        int* __restrict__ csb) {
    const int bid = blockIdx.x;
    if (bid < 576) {
        int idx = bid * 256 + threadIdx.x;      // = e*2304 + j, 147456 total
        int e = idx / UNIT;
        int j = idx - e * UNIT;
        int s = j / 72, r = j - s * 72;
        int tap, h;
        if (r < 64) { tap = r & 7; h = s*8 + (r >> 3); }
        else        { tap = 8;     h = s*8 + (r - 64); }
        float v;
        if (tap == 0)      v = w1[h*EE + e];
        else if (tap <= 3) v = w3[(h*EE + e)*3 + (tap-1)];
        else               v = w5[(h*EE + e)*5 + (tap-4)];
        wTp[idx] = v;
    } else if (bid < 768) {
        int i = ((bid - 576) * 256 + threadIdx.x) * 4;
        float4 v = *(const float4*)(lw + i);
        ushort4 o4;
        o4.x = f2bs(v.x); o4.y = f2bs(v.y); o4.z = f2bs(v.z); o4.w = f2bs(v.w);
        *(ushort4*)(lwb + i) = o4;
    } else {
        int i = (bid - 768) * 256 + threadIdx.x;  // 640*256 = 163840 = NW*WW
        csb[i] = chars[i] * 144;
    }
}

// K1: P5[v][j] = sum_e emb[v][e] * wTp[e][j]. 4 vocab rows per block,
// grid (64, 9) x 256 thr. Coalesced streaming reads/writes.
__global__ __launch_bounds__(256) void build_tables(
        const float* __restrict__ emb,
        const float* __restrict__ wTp,
        ushort* __restrict__ P5) {
    __shared__ float emb_s[4][EE];
    const int v0 = blockIdx.x * 4;
    const int j  = blockIdx.y * 256 + threadIdx.x;
    const int t  = threadIdx.x;
    emb_s[t >> 6][t & 63] = emb[v0*EE + t];
    __syncthreads();

    float a0 = 0.f, a1 = 0.f, a2 = 0.f, a3 = 0.f;
    const float* wp = wTp + j;
    #pragma unroll 8
    for (int e = 0; e < EE; ++e) {
        float w = wp[e * UNIT];
        a0 += emb_s[0][e] * w; a1 += emb_s[1][e] * w;
        a2 += emb_s[2][e] * w; a3 += emb_s[3][e] * w;
    }
    P5[(size_t)(v0+0)*UNIT + j] = f2bs(a0);
    P5[(size_t)(v0+1)*UNIT + j] = f2bs(a1);
    P5[(size_t)(v0+2)*UNIT + j] = f2bs(a2);
    P5[(size_t)(v0+3)*UNIT + j] = f2bs(a3);
}

// ---------------------------------------------------------------------------
// K2: conv+relu+maxpool. R19 lane re-map (current best, 129.8us): 8 lanes
// per word, ONE h each (lane = w*8 + r reads row c_w chunk r). Bank-quad
// index = (c_w + r) mod 8, so each word's 8 lanes cover all 8 quads exactly
// once -> deterministically conflict-free for any char distribution.
// Structural floor: 755 MB LDS reads at ~85 B/cy/CU ~= 20 us; VALU ~13 us
// overlapped. Left untouched this round.
// ---------------------------------------------------------------------------
__global__ __launch_bounds__(256, 4) void conv_pool(
        const int* __restrict__ csb,       // pre-scaled char byte offsets
        const ushort* __restrict__ P5,
        const float* __restrict__ b1,
        const float* __restrict__ b3,
        const float* __restrict__ b5,
        ushort* __restrict__ outs) {
    __shared__ uint4 tileq[2304];          // 36864 B table slice
    const int t = threadIdx.x;
    const int g = blockIdx.x;              // word group 0..31 (256 words)
    const int s = blockIdx.y;              // h slice   0..31

    {   // stage table slice: 2304 16-B chunks, 9 per thread (proven code)
        const char* src = (const char*)P5 + (size_t)s * 144;
        char* dst = (char*)tileq;
        #pragma unroll
        for (int i = 0; i < 9; ++i) {
            int c = i*256 + t;
            int v = c / 9, k = c - 9*v;
            *(uint4*)(dst + v*144 + k*16) =
                *(const uint4*)(src + (size_t)v*4608 + k*16);
        }
    }
    __syncthreads();

    const int r   = t & 7;                 // h lane 0..7 (chunk index)
    const int wl0 = t >> 3;                // word lane 0..31
    const char* tileQ = (const char*)tileq + r*16;        // taps 0..7 row
    const char* tileT = (const char*)tileq + 128 + r*2;   // tap8 ushort
    const int h = s*8 + r;
    const float bb1 = b1[h], bb3 = b3[h], bb5 = b5[h];

    #pragma unroll
    for (int cc = 0; cc < 8; ++cc) {
        const int wl = cc*32 + wl0;
        const int n  = g*256 + wl;

        // this word's pre-scaled char offsets: 5 aligned int4 (L2-hot, 80 B)
        int cw[WW];
        {
            const int4* cp = (const int4*)(csb + n * WW);
            #pragma unroll
            for (int i = 0; i < 5; ++i) {
                int4 v = cp[i];
                cw[i*4+0] = v.x; cw[i*4+1] = v.y;
                cw[i*4+2] = v.z; cw[i*4+3] = v.w;
            }
        }

        float a3[3], a5[5], m1, m3, m5;
        a3[0] = 0.f; a5[0] = 0.f; a5[1] = 0.f;
        m1 = -1e30f; m3 = -1e30f; m5 = -1e30f;

        uint4 q[2]; ushort t8[2];
        q[0]  = *(const uint4*)(tileQ + cw[0]);
        t8[0] = *(const ushort*)(tileT + cw[0]);

        #pragma unroll
        for (int j = 0; j < WW; ++j) {
            const int cur = j & 1, nxt = cur ^ 1;
            if (j + 1 < WW) {               // prefetch char j+1
                q[nxt]  = *(const uint4*)(tileQ + cw[j+1]);
                t8[nxt] = *(const ushort*)(tileT + cw[j+1]);
            }
            float t8v = blo(t8[cur]);
            STEP(j, q[cur], t8v, a3, a5, m1, m3, m5);
        }
        m3 = fmaxf(m3, a3[(WW-1)%3]);      // pos 19
        m5 = fmaxf(m5, a5[(WW-2)%5]);      // pos 18
        m5 = fmaxf(m5, a5[(WW-1)%5]);      // pos 19

        ushort* op = outs + (size_t)n * K3 + h;
        op[0*HH] = f2bs(fmaxf(m1 + bb1, 0.f));
        op[1*HH] = f2bs(fmaxf(m3 + bb3, 0.f));
        op[2*HH] = f2bs(fmaxf(m5 + bb5, 0.f));
    }
}

// ---------------------------------------------------------------------------
// K3: out = outs @ lw^T + lb via MFMA 16x16x32.
// R20: 64m x 64n per block, 4 waves (2x2 arrangement of the proven 32x32
// wave tile), grid (128, 4) = 512 blocks (2 blocks/CU = 2 waves/SIMD, same
// as before). Halves L2/L3 operand traffic vs (256,8)x1-wave: A fetched
// 4x (was 8x) = 50 MB, B fetched 128x (was 256x) = 50 MB. Per-wave inner
// loop, fragment layout, prefetch (distance-3), and numerics unchanged.
// A[m][k]: m=lane&15, k=quad*8+j. B[k][n]=lw[n][k]: n=lane&15, k=quad*8+j.
// C/D: col=lane&15, row=quad*4+reg.
// ---------------------------------------------------------------------------
__global__ __launch_bounds__(256) void gemm_out(
        const ushort* __restrict__ outs,   // [8192][768] bf16
        const ushort* __restrict__ lwb,    // [256][768] bf16
        const float* __restrict__ lb,
        float* __restrict__ out) {
    const int lane = threadIdx.x & 63;
    const int w    = threadIdx.x >> 6;     // wave 0..3
    const int m0 = blockIdx.x * 64 + (w >> 1) * 32;
    const int n0 = blockIdx.y * 64 + (w & 1) * 32;
    const int mrow = lane & 15, quad = lane >> 4;

    f32x4 acc00 = (f32x4){0,0,0,0}, acc01 = (f32x4){0,0,0,0};
    f32x4 acc10 = (f32x4){0,0,0,0}, acc11 = (f32x4){0,0,0,0};
    const ushort* ap = outs + (size_t)(m0 + mrow) * K3 + quad * 8;
    const ushort* bp = lwb  + (size_t)(n0 + mrow) * K3 + quad * 8;

    bf16x8 A0[4], A1[4], B0[4], B1[4];
    #pragma unroll
    for (int pi = 0; pi < 3; ++pi) {
        A0[pi] = *(const bf16x8*)(ap + pi*32);
        A1[pi] = *(const bf16x8*)(ap + 16*K3 + pi*32);
        B0[pi] = *(const bf16x8*)(bp + pi*32);
        B1[pi] = *(const bf16x8*)(bp + 16*K3 + pi*32);
    }

    #pragma unroll
    for (int it = 0; it < K3/32; ++it) {
        const int sl = it & 3;
        const int nl = (it + 3) & 3;
        const int kn = (it + 3 < K3/32) ? (it + 3) * 32 : 0;   // wrap: harmless
        A0[nl] = *(const bf16x8*)(ap + kn);
        A1[nl] = *(const bf16x8*)(ap + 16*K3 + kn);
        B0[nl] = *(const bf16x8*)(bp + kn);
        B1[nl] = *(const bf16x8*)(bp + 16*K3 + kn);
        acc00 = __builtin_amdgcn_mfma_f32_16x16x32_bf16(A0[sl], B0[sl], acc00, 0, 0, 0);
        acc01 = __builtin_amdgcn_mfma_f32_16x16x32_bf16(A0[sl], B1[sl], acc01, 0, 0, 0);
        acc10 = __builtin_amdgcn_mfma_f32_16x16x32_bf16(A1[sl], B0[sl], acc10, 0, 0, 0);
        acc11 = __builtin_amdgcn_mfma_f32_16x16x32_bf16(A1[sl], B1[sl], acc11, 0, 0, 0);
    }

    #pragma unroll
    for (int i = 0; i < 2; ++i) {
        #pragma unroll
        for (int jn = 0; jn < 2; ++jn) {
            const f32x4 acc = (i==0) ? (jn==0 ? acc00 : acc01)
                                     : (jn==0 ? acc10 : acc11);
            int ncol = n0 + jn*16 + mrow;
            float lbv = lb[ncol];
            #pragma unroll
            for (int r = 0; r < 4; ++r)
                out[(size_t)(m0 + i*16 + quad*4 + r)*HH + ncol] = acc[r] + lbv;
        }
    }
}

// ---------------------------------------------------------------------------
extern "C" void kernel_launch(void* const* d_in, const int* in_sizes, int n_in,
                              void* d_out, int out_size, void* d_ws, size_t ws_size,
                              hipStream_t stream) {
    const int*   chars = (const int*)d_in[0];
    const float* emb   = (const float*)d_in[1];
    const float* w1    = (const float*)d_in[2];
    const float* b1    = (const float*)d_in[3];
    const float* w3    = (const float*)d_in[4];
    const float* b3    = (const float*)d_in[5];
    const float* w5    = (const float*)d_in[6];
    const float* b5    = (const float*)d_in[7];
    const float* lw    = (const float*)d_in[8];
    const float* lb    = (const float*)d_in[9];

    // ws: P5 [256][2304] bf16 (1.18MB) | wTp [64][2304] f32 (0.59MB)
    //   | outs [8192][768] bf16 (12.6MB) | lwb [256][768] bf16 (0.39MB)
    //   | csb [8192*20] int (0.66MB)
    ushort* P5   = (ushort*)d_ws;
    float*  wTp  = (float*)(P5 + VOCAB * UNIT);
    ushort* outs = (ushort*)(wTp + EE * UNIT);
    ushort* lwb  = outs + (size_t)NW * K3;
    int*    csb  = (int*)(lwb + (size_t)VOCAB * K3);

    prep<<<1408, 256, 0, stream>>>(chars, w1, w3, w5, lw, wTp, lwb, csb);
    build_tables<<<dim3(VOCAB/4, 9), 256, 0, stream>>>(emb, wTp, P5);
    conv_pool<<<dim3(NW/256, 32), 256, 0, stream>>>(csb, P5, b1, b3, b5, outs);
    gemm_out<<<dim3(NW/64, HH/64), 256, 0, stream>>>(outs, lwb, lb, (float*)d_out);
}

// Round 8
// 131.135 us; speedup vs baseline: 1.0028x; 1.0028x over previous
//
#include <hip/hip_runtime.h>
#include <hip/hip_bf16.h>

#define WW 20
#define NW 8192         // 64*128 words
#define VOCAB 256
#define EE 64
#define HH 256
#define K3 768          // 3*HH
#define UNIT 2304       // ushorts per vocab unit (P5) = 4608 B

typedef short bf16x8 __attribute__((ext_vector_type(8)));
typedef float f32x4  __attribute__((ext_vector_type(4)));

__device__ __forceinline__ ushort f2bs(float x) {
    __hip_bfloat16 h = __float2bfloat16(x);
    union { __hip_bfloat16 h; ushort u; } c; c.h = h; return c.u;
}
__device__ __forceinline__ float blo(unsigned u) {
    union { unsigned i; float f; } c; c.i = u << 16; return c.f;
}
__device__ __forceinline__ float bhi(unsigned u) {
    union { unsigned i; float f; } c; c.i = u & 0xffff0000u; return c.f;
}

// sliding-window update for one h given this char's 9 bf16 taps.
// j compile-time (fully unrolled caller) so %3/%5 indices and guards fold.
// R17 lesson: no f32x2 packing (VGPR 220 > 128 cliff, halved occupancy).
#define STEP(j, qq, t8v, a3, a5, mm1, mm3, mm5) {                        \
    float t0 = blo((qq).x), t1 = bhi((qq).x);                            \
    float t2 = blo((qq).y), t3 = bhi((qq).y);                            \
    float t4 = blo((qq).z), t5 = bhi((qq).z);                            \
    float t6 = blo((qq).w), t7 = bhi((qq).w);                            \
    mm1 = fmaxf(mm1, t0);                                                \
    if ((j) + 1 < WW) a3[((j)+1)%3] = t1;                                \
    a3[(j)%3] += t2;                                                     \
    if ((j) >= 1) { a3[((j)-1)%3] += t3;                                 \
                    mm3 = fmaxf(mm3, a3[((j)-1)%3]); }                   \
    if ((j) + 2 < WW) a5[((j)+2)%5] = t4;                                \
    if ((j) + 1 < WW) a5[((j)+1)%5] += t5;                               \
    a5[(j)%5] += t6;                                                     \
    if ((j) >= 1) a5[((j)-1)%5] += t7;                                   \
    if ((j) >= 2) { a5[((j)-2)%5] += (t8v);                              \
                    mm5 = fmaxf(mm5, a5[((j)-2)%5]); }                   \
}

// ---------------------------------------------------------------------------
// P5 layout (per vocab v, 2304 ushorts = 4608 B): 32 slices s of 144 B:
//   [hl 0..7][taps 0..7] (8 x 16 B rows), then [tap8 for hl 0..7] (16 B).
// bf16 kept deliberately (R12: f32 table doubled traffic + conflicts).
// R14 lesson: keep the wTp round-trip (fused divergent gather cost +6.6us).
// R18 lesson: tap8 must stay in LDS (global scatter = 335 MB L2 traffic).
// R20 lesson: gemm 64x64/4-wave block: +1.7us (A-panel L2 locality was
// already optimal under y-major bid: all n-blocks of an m share bid%8).
// ---------------------------------------------------------------------------

// K0: prep. blocks 0..575: wTp[e][j] f32 (P5 column order);
//     blocks 576..767: lw f32 -> bf16;
//     blocks 768..1407: csb[i] = chars[i]*144 (pre-scaled byte offsets,
//     removes the *144 from conv's hot loop).
__global__ __launch_bounds__(256) void prep(
        const int* __restrict__ chars,
        const float* __restrict__ w1,
        const float* __restrict__ w3,
        const float* __restrict__ w5,
        const float* __restrict__ lw,
        float* __restrict__ wTp,
        ushort* __restrict__ lwb,
        int* __restrict__ csb) {
    const int bid = blockIdx.x;
    if (bid < 576) {
        int idx = bid * 256 + threadIdx.x;      // = e*2304 + j, 147456 total
        int e = idx / UNIT;
        int j = idx - e * UNIT;
        int s = j / 72, r = j - s * 72;
        int tap, h;
        if (r < 64) { tap = r & 7; h = s*8 + (r >> 3); }
        else        { tap = 8;     h = s*8 + (r - 64); }
        float v;
        if (tap == 0)      v = w1[h*EE + e];
        else if (tap <= 3) v = w3[(h*EE + e)*3 + (tap-1)];
        else               v = w5[(h*EE + e)*5 + (tap-4)];
        wTp[idx] = v;
    } else if (bid < 768) {
        int i = ((bid - 576) * 256 + threadIdx.x) * 4;
        float4 v = *(const float4*)(lw + i);
        ushort4 o4;
        o4.x = f2bs(v.x); o4.y = f2bs(v.y); o4.z = f2bs(v.z); o4.w = f2bs(v.w);
        *(ushort4*)(lwb + i) = o4;
    } else {
        int i = (bid - 768) * 256 + threadIdx.x;  // 640*256 = 163840 = NW*WW
        csb[i] = chars[i] * 144;
    }
}

// K1: P5[v][j] = sum_e emb[v][e] * wTp[e][j]. 4 vocab rows per block,
// grid (64, 9) x 256 thr. Coalesced streaming reads/writes.
__global__ __launch_bounds__(256) void build_tables(
        const float* __restrict__ emb,
        const float* __restrict__ wTp,
        ushort* __restrict__ P5) {
    __shared__ float emb_s[4][EE];
    const int v0 = blockIdx.x * 4;
    const int j  = blockIdx.y * 256 + threadIdx.x;
    const int t  = threadIdx.x;
    emb_s[t >> 6][t & 63] = emb[v0*EE + t];
    __syncthreads();

    float a0 = 0.f, a1 = 0.f, a2 = 0.f, a3 = 0.f;
    const float* wp = wTp + j;
    #pragma unroll 8
    for (int e = 0; e < EE; ++e) {
        float w = wp[e * UNIT];
        a0 += emb_s[0][e] * w; a1 += emb_s[1][e] * w;
        a2 += emb_s[2][e] * w; a3 += emb_s[3][e] * w;
    }
    P5[(size_t)(v0+0)*UNIT + j] = f2bs(a0);
    P5[(size_t)(v0+1)*UNIT + j] = f2bs(a1);
    P5[(size_t)(v0+2)*UNIT + j] = f2bs(a2);
    P5[(size_t)(v0+3)*UNIT + j] = f2bs(a3);
}

// ---------------------------------------------------------------------------
// K2: conv+relu+maxpool. R19 lane re-map (proven, 129.8us): 8 lanes per
// word, ONE h each (lane = w*8 + r reads row c_w chunk r). Bank-quad index
// = (c_w + r) mod 8: each word's 8 lanes cover all 8 quads exactly once ->
// deterministically conflict-free for any char distribution.
// R21: staging via global_load_lds width=16 (compiler never auto-emits;
// Common-mistake #1). Key: dst offset v*144+k*16 = (9v+k)*16 = c*16 is
// LINEAR in chunk id c = i*256+t, so per wave dst = uniform base
// (i*4096+w*1024) + lane*16 -- exactly the DMA's required form; src stays
// per-lane scattered (allowed). Removes 9 dwordx4 + 9 ds_write per thread.
// __syncthreads() drains vmcnt before use.
// ---------------------------------------------------------------------------
__global__ __launch_bounds__(256, 4) void conv_pool(
        const int* __restrict__ csb,       // pre-scaled char byte offsets
        const ushort* __restrict__ P5,
        const float* __restrict__ b1,
        const float* __restrict__ b3,
        const float* __restrict__ b5,
        ushort* __restrict__ outs) {
    __shared__ uint4 tileq[2304];          // 36864 B table slice
    const int t = threadIdx.x;
    const int g = blockIdx.x;              // word group 0..31 (256 words)
    const int s = blockIdx.y;              // h slice   0..31

    {   // stage table slice: 2304 16-B chunks via global->LDS DMA
        const char* src = (const char*)P5 + (size_t)s * 144;
        const int wbase = (t & ~63) * 16;  // wave-uniform dst component
        #pragma unroll
        for (int i = 0; i < 9; ++i) {
            int c = i*256 + t;
            int v = c / 9, k = c - 9*v;
            __builtin_amdgcn_global_load_lds(
                (const __attribute__((address_space(1))) void*)
                    (src + (size_t)v*4608 + k*16),
                (__attribute__((address_space(3))) void*)
                    ((char*)tileq + i*4096 + wbase),
                16, 0, 0);
        }
    }
    __syncthreads();

    const int r   = t & 7;                 // h lane 0..7 (chunk index)
    const int wl0 = t >> 3;                // word lane 0..31
    const char* tileQ = (const char*)tileq + r*16;        // taps 0..7 row
    const char* tileT = (const char*)tileq + 128 + r*2;   // tap8 ushort
    const int h = s*8 + r;
    const float bb1 = b1[h], bb3 = b3[h], bb5 = b5[h];

    #pragma unroll
    for (int cc = 0; cc < 8; ++cc) {
        const int wl = cc*32 + wl0;
        const int n  = g*256 + wl;

        // this word's pre-scaled char offsets: 5 aligned int4 (L2-hot, 80 B)
        int cw[WW];
        {
            const int4* cp = (const int4*)(csb + n * WW);
            #pragma unroll
            for (int i = 0; i < 5; ++i) {
                int4 v = cp[i];
                cw[i*4+0] = v.x; cw[i*4+1] = v.y;
                cw[i*4+2] = v.z; cw[i*4+3] = v.w;
            }
        }

        float a3[3], a5[5], m1, m3, m5;
        a3[0] = 0.f; a5[0] = 0.f; a5[1] = 0.f;
        m1 = -1e30f; m3 = -1e30f; m5 = -1e30f;

        uint4 q[2]; ushort t8[2];
        q[0]  = *(const uint4*)(tileQ + cw[0]);
        t8[0] = *(const ushort*)(tileT + cw[0]);

        #pragma unroll
        for (int j = 0; j < WW; ++j) {
            const int cur = j & 1, nxt = cur ^ 1;
            if (j + 1 < WW) {               // prefetch char j+1
                q[nxt]  = *(const uint4*)(tileQ + cw[j+1]);
                t8[nxt] = *(const ushort*)(tileT + cw[j+1]);
            }
            float t8v = blo(t8[cur]);
            STEP(j, q[cur], t8v, a3, a5, m1, m3, m5);
        }
        m3 = fmaxf(m3, a3[(WW-1)%3]);      // pos 19
        m5 = fmaxf(m5, a5[(WW-2)%5]);      // pos 18
        m5 = fmaxf(m5, a5[(WW-1)%5]);      // pos 19

        ushort* op = outs + (size_t)n * K3 + h;
        op[0*HH] = f2bs(fmaxf(m1 + bb1, 0.f));
        op[1*HH] = f2bs(fmaxf(m3 + bb3, 0.f));
        op[2*HH] = f2bs(fmaxf(m5 + bb5, 0.f));
    }
}

// ---------------------------------------------------------------------------
// K3: out = outs @ lw^T + lb via MFMA 16x16x32. 32m x 32n per wave,
// grid (256, 8) = 2048 single-wave blocks (R19-proven config, reverted from
// R20's 64x64/4-wave which cost +1.7us). 4-slot / distance-3 prefetch.
// A[m][k]: m=lane&15, k=quad*8+j. B[k][n]=lw[n][k]: n=lane&15, k=quad*8+j.
// C/D: col=lane&15, row=quad*4+reg.
// ---------------------------------------------------------------------------
__global__ __launch_bounds__(64) void gemm_out(
        const ushort* __restrict__ outs,   // [8192][768] bf16
        const ushort* __restrict__ lwb,    // [256][768] bf16
        const float* __restrict__ lb,
        float* __restrict__ out) {
    const int lane = threadIdx.x;
    const int m0 = blockIdx.x * 32;
    const int n0 = blockIdx.y * 32;
    const int mrow = lane & 15, quad = lane >> 4;

    f32x4 acc00 = (f32x4){0,0,0,0}, acc01 = (f32x4){0,0,0,0};
    f32x4 acc10 = (f32x4){0,0,0,0}, acc11 = (f32x4){0,0,0,0};
    const ushort* ap = outs + (size_t)(m0 + mrow) * K3 + quad * 8;
    const ushort* bp = lwb  + (size_t)(n0 + mrow) * K3 + quad * 8;

    bf16x8 A0[4], A1[4], B0[4], B1[4];
    #pragma unroll
    for (int pi = 0; pi < 3; ++pi) {
        A0[pi] = *(const bf16x8*)(ap + pi*32);
        A1[pi] = *(const bf16x8*)(ap + 16*K3 + pi*32);
        B0[pi] = *(const bf16x8*)(bp + pi*32);
        B1[pi] = *(const bf16x8*)(bp + 16*K3 + pi*32);
    }

    #pragma unroll
    for (int it = 0; it < K3/32; ++it) {
        const int sl = it & 3;
        const int nl = (it + 3) & 3;
        const int kn = (it + 3 < K3/32) ? (it + 3) * 32 : 0;   // wrap: harmless
        A0[nl] = *(const bf16x8*)(ap + kn);
        A1[nl] = *(const bf16x8*)(ap + 16*K3 + kn);
        B0[nl] = *(const bf16x8*)(bp + kn);
        B1[nl] = *(const bf16x8*)(bp + 16*K3 + kn);
        acc00 = __builtin_amdgcn_mfma_f32_16x16x32_bf16(A0[sl], B0[sl], acc00, 0, 0, 0);
        acc01 = __builtin_amdgcn_mfma_f32_16x16x32_bf16(A0[sl], B1[sl], acc01, 0, 0, 0);
        acc10 = __builtin_amdgcn_mfma_f32_16x16x32_bf16(A1[sl], B0[sl], acc10, 0, 0, 0);
        acc11 = __builtin_amdgcn_mfma_f32_16x16x32_bf16(A1[sl], B1[sl], acc11, 0, 0, 0);
    }

    #pragma unroll
    for (int i = 0; i < 2; ++i) {
        #pragma unroll
        for (int jn = 0; jn < 2; ++jn) {
            const f32x4 acc = (i==0) ? (jn==0 ? acc00 : acc01)
                                     : (jn==0 ? acc10 : acc11);
            int ncol = n0 + jn*16 + mrow;
            float lbv = lb[ncol];
            #pragma unroll
            for (int r = 0; r < 4; ++r)
                out[(size_t)(m0 + i*16 + quad*4 + r)*HH + ncol] = acc[r] + lbv;
        }
    }
}

// ---------------------------------------------------------------------------
extern "C" void kernel_launch(void* const* d_in, const int* in_sizes, int n_in,
                              void* d_out, int out_size, void* d_ws, size_t ws_size,
                              hipStream_t stream) {
    const int*   chars = (const int*)d_in[0];
    const float* emb   = (const float*)d_in[1];
    const float* w1    = (const float*)d_in[2];
    const float* b1    = (const float*)d_in[3];
    const float* w3    = (const float*)d_in[4];
    const float* b3    = (const float*)d_in[5];
    const float* w5    = (const float*)d_in[6];
    const float* b5    = (const float*)d_in[7];
    const float* lw    = (const float*)d_in[8];
    const float* lb    = (const float*)d_in[9];

    // ws: P5 [256][2304] bf16 (1.18MB) | wTp [64][2304] f32 (0.59MB)
    //   | outs [8192][768] bf16 (12.6MB) | lwb [256][768] bf16 (0.39MB)
    //   | csb [8192*20] int (0.66MB)
    ushort* P5   = (ushort*)d_ws;
    float*  wTp  = (float*)(P5 + VOCAB * UNIT);
    ushort* outs = (ushort*)(wTp + EE * UNIT);
    ushort* lwb  = outs + (size_t)NW * K3;
    int*    csb  = (int*)(lwb + (size_t)VOCAB * K3);

    prep<<<1408, 256, 0, stream>>>(chars, w1, w3, w5, lw, wTp, lwb, csb);
    build_tables<<<dim3(VOCAB/4, 9), 256, 0, stream>>>(emb, wTp, P5);
    conv_pool<<<dim3(NW/256, 32), 256, 0, stream>>>(csb, P5, b1, b3, b5, outs);
    gemm_out<<<dim3(NW/32, HH/32), 64, 0, stream>>>(outs, lwb, lb, (float*)d_out);
}

// Round 9
// 130.280 us; speedup vs baseline: 1.0094x; 1.0066x over previous
//
#include <hip/hip_runtime.h>
#include <hip/hip_bf16.h>

#define WW 20
#define NW 8192         // 64*128 words
#define VOCAB 256
#define EE 64
#define HH 256
#define K3 768          // 3*HH
#define UNIT 2304       // ushorts per vocab unit (P5) = 4608 B

typedef short bf16x8 __attribute__((ext_vector_type(8)));
typedef float f32x4  __attribute__((ext_vector_type(4)));

__device__ __forceinline__ ushort f2bs(float x) {
    __hip_bfloat16 h = __float2bfloat16(x);
    union { __hip_bfloat16 h; ushort u; } c; c.h = h; return c.u;
}
__device__ __forceinline__ float blo(unsigned u) {
    union { unsigned i; float f; } c; c.i = u << 16; return c.f;
}
__device__ __forceinline__ float bhi(unsigned u) {
    union { unsigned i; float f; } c; c.i = u & 0xffff0000u; return c.f;
}

// sliding-window update for one h given this char's 9 bf16 taps.
// j compile-time (fully unrolled caller) so %3/%5 indices and guards fold.
// R17 lesson: no f32x2 packing (VGPR 220 > 128 cliff, halved occupancy).
#define STEP(j, qq, t8v, a3, a5, mm1, mm3, mm5) {                        \
    float t0 = blo((qq).x), t1 = bhi((qq).x);                            \
    float t2 = blo((qq).y), t3 = bhi((qq).y);                            \
    float t4 = blo((qq).z), t5 = bhi((qq).z);                            \
    float t6 = blo((qq).w), t7 = bhi((qq).w);                            \
    mm1 = fmaxf(mm1, t0);                                                \
    if ((j) + 1 < WW) a3[((j)+1)%3] = t1;                                \
    a3[(j)%3] += t2;                                                     \
    if ((j) >= 1) { a3[((j)-1)%3] += t3;                                 \
                    mm3 = fmaxf(mm3, a3[((j)-1)%3]); }                   \
    if ((j) + 2 < WW) a5[((j)+2)%5] = t4;                                \
    if ((j) + 1 < WW) a5[((j)+1)%5] += t5;                               \
    a5[(j)%5] += t6;                                                     \
    if ((j) >= 1) a5[((j)-1)%5] += t7;                                   \
    if ((j) >= 2) { a5[((j)-2)%5] += (t8v);                              \
                    mm5 = fmaxf(mm5, a5[((j)-2)%5]); }                   \
}

// ---------------------------------------------------------------------------
// P5 layout (per vocab v, 2304 ushorts = 4608 B): 32 slices s of 144 B:
//   [hl 0..7][taps 0..7] (8 x 16 B rows), then [tap8 for hl 0..7] (16 B).
// bf16 kept deliberately (R12: f32 table doubled traffic + conflicts).
// R14: keep the wTp round-trip (fused divergent gather cost +6.6us).
// R18: tap8 must stay in LDS (global scatter = 335 MB L2 traffic).
// R20: gemm 64x64/4-wave block regressed (+1.7us) -- A-panel L2 locality
//      already optimal under y-major bid (n-blocks of an m share bid%8).
// R21: global_load_lds staging neutral-to-negative (~+1us) -- scattered
//      per-lane src serializes the same; no occupancy win available.
// This file = the measured-best R19 configuration (129.8us).
// ---------------------------------------------------------------------------

// K0: prep. blocks 0..575: wTp[e][j] f32 (P5 column order);
//     blocks 576..767: lw f32 -> bf16;
//     blocks 768..1407: csb[i] = chars[i]*144 (pre-scaled byte offsets,
//     removes the *144 from conv's hot loop).
__global__ __launch_bounds__(256) void prep(
        const int* __restrict__ chars,
        const float* __restrict__ w1,
        const float* __restrict__ w3,
        const float* __restrict__ w5,
        const float* __restrict__ lw,
        float* __restrict__ wTp,
        ushort* __restrict__ lwb,
        int* __restrict__ csb) {
    const int bid = blockIdx.x;
    if (bid < 576) {
        int idx = bid * 256 + threadIdx.x;      // = e*2304 + j, 147456 total
        int e = idx / UNIT;
        int j = idx - e * UNIT;
        int s = j / 72, r = j - s * 72;
        int tap, h;
        if (r < 64) { tap = r & 7; h = s*8 + (r >> 3); }
        else        { tap = 8;     h = s*8 + (r - 64); }
        float v;
        if (tap == 0)      v = w1[h*EE + e];
        else if (tap <= 3) v = w3[(h*EE + e)*3 + (tap-1)];
        else               v = w5[(h*EE + e)*5 + (tap-4)];
        wTp[idx] = v;
    } else if (bid < 768) {
        int i = ((bid - 576) * 256 + threadIdx.x) * 4;
        float4 v = *(const float4*)(lw + i);
        ushort4 o4;
        o4.x = f2bs(v.x); o4.y = f2bs(v.y); o4.z = f2bs(v.z); o4.w = f2bs(v.w);
        *(ushort4*)(lwb + i) = o4;
    } else {
        int i = (bid - 768) * 256 + threadIdx.x;  // 640*256 = 163840 = NW*WW
        csb[i] = chars[i] * 144;
    }
}

// K1: P5[v][j] = sum_e emb[v][e] * wTp[e][j]. 4 vocab rows per block,
// grid (64, 9) x 256 thr. Coalesced streaming reads/writes.
__global__ __launch_bounds__(256) void build_tables(
        const float* __restrict__ emb,
        const float* __restrict__ wTp,
        ushort* __restrict__ P5) {
    __shared__ float emb_s[4][EE];
    const int v0 = blockIdx.x * 4;
    const int j  = blockIdx.y * 256 + threadIdx.x;
    const int t  = threadIdx.x;
    emb_s[t >> 6][t & 63] = emb[v0*EE + t];
    __syncthreads();

    float a0 = 0.f, a1 = 0.f, a2 = 0.f, a3 = 0.f;
    const float* wp = wTp + j;
    #pragma unroll 8
    for (int e = 0; e < EE; ++e) {
        float w = wp[e * UNIT];
        a0 += emb_s[0][e] * w; a1 += emb_s[1][e] * w;
        a2 += emb_s[2][e] * w; a3 += emb_s[3][e] * w;
    }
    P5[(size_t)(v0+0)*UNIT + j] = f2bs(a0);
    P5[(size_t)(v0+1)*UNIT + j] = f2bs(a1);
    P5[(size_t)(v0+2)*UNIT + j] = f2bs(a2);
    P5[(size_t)(v0+3)*UNIT + j] = f2bs(a3);
}

// ---------------------------------------------------------------------------
// K2: conv+relu+maxpool. R19 lane re-map (measured best): 8 lanes per word,
// ONE h each (lane = w*8 + r reads row c_w chunk r). Bank-quad index =
// (c_w + r) mod 8: each word's 8 lanes cover all 8 quads exactly once ->
// deterministically conflict-free for any char distribution (old 4-lane/2-h
// map had only c mod 8 entropy -> 5.1M conflict cycles).
// Structural floor: 755 MB conflict-free LDS reads ~= 20 us; VALU ~13 us
// overlapped. VGPR-staged staging (R21's DMA staging was ~+1us).
// ---------------------------------------------------------------------------
__global__ __launch_bounds__(256, 4) void conv_pool(
        const int* __restrict__ csb,       // pre-scaled char byte offsets
        const ushort* __restrict__ P5,
        const float* __restrict__ b1,
        const float* __restrict__ b3,
        const float* __restrict__ b5,
        ushort* __restrict__ outs) {
    __shared__ uint4 tileq[2304];          // 36864 B table slice
    const int t = threadIdx.x;
    const int g = blockIdx.x;              // word group 0..31 (256 words)
    const int s = blockIdx.y;              // h slice   0..31

    {   // stage table slice: 2304 16-B chunks, 9 per thread (proven code)
        const char* src = (const char*)P5 + (size_t)s * 144;
        char* dst = (char*)tileq;
        #pragma unroll
        for (int i = 0; i < 9; ++i) {
            int c = i*256 + t;
            int v = c / 9, k = c - 9*v;
            *(uint4*)(dst + v*144 + k*16) =
                *(const uint4*)(src + (size_t)v*4608 + k*16);
        }
    }
    __syncthreads();

    const int r   = t & 7;                 // h lane 0..7 (chunk index)
    const int wl0 = t >> 3;                // word lane 0..31
    const char* tileQ = (const char*)tileq + r*16;        // taps 0..7 row
    const char* tileT = (const char*)tileq + 128 + r*2;   // tap8 ushort
    const int h = s*8 + r;
    const float bb1 = b1[h], bb3 = b3[h], bb5 = b5[h];

    #pragma unroll
    for (int cc = 0; cc < 8; ++cc) {
        const int wl = cc*32 + wl0;
        const int n  = g*256 + wl;

        // this word's pre-scaled char offsets: 5 aligned int4 (L2-hot, 80 B)
        int cw[WW];
        {
            const int4* cp = (const int4*)(csb + n * WW);
            #pragma unroll
            for (int i = 0; i < 5; ++i) {
                int4 v = cp[i];
                cw[i*4+0] = v.x; cw[i*4+1] = v.y;
                cw[i*4+2] = v.z; cw[i*4+3] = v.w;
            }
        }

        float a3[3], a5[5], m1, m3, m5;
        a3[0] = 0.f; a5[0] = 0.f; a5[1] = 0.f;
        m1 = -1e30f; m3 = -1e30f; m5 = -1e30f;

        uint4 q[2]; ushort t8[2];
        q[0]  = *(const uint4*)(tileQ + cw[0]);
        t8[0] = *(const ushort*)(tileT + cw[0]);

        #pragma unroll
        for (int j = 0; j < WW; ++j) {
            const int cur = j & 1, nxt = cur ^ 1;
            if (j + 1 < WW) {               // prefetch char j+1
                q[nxt]  = *(const uint4*)(tileQ + cw[j+1]);
                t8[nxt] = *(const ushort*)(tileT + cw[j+1]);
            }
            float t8v = blo(t8[cur]);
            STEP(j, q[cur], t8v, a3, a5, m1, m3, m5);
        }
        m3 = fmaxf(m3, a3[(WW-1)%3]);      // pos 19
        m5 = fmaxf(m5, a5[(WW-2)%5]);      // pos 18
        m5 = fmaxf(m5, a5[(WW-1)%5]);      // pos 19

        ushort* op = outs + (size_t)n * K3 + h;
        op[0*HH] = f2bs(fmaxf(m1 + bb1, 0.f));
        op[1*HH] = f2bs(fmaxf(m3 + bb3, 0.f));
        op[2*HH] = f2bs(fmaxf(m5 + bb5, 0.f));
    }
}

// ---------------------------------------------------------------------------
// K3: out = outs @ lw^T + lb via MFMA 16x16x32. 32m x 32n per wave,
// grid (256, 8) = 2048 single-wave blocks (measured-best config).
// 4-slot / distance-3 prefetch. Fully unrolled K so slot indices fold.
// A[m][k]: m=lane&15, k=quad*8+j. B[k][n]=lw[n][k]: n=lane&15, k=quad*8+j.
// C/D: col=lane&15, row=quad*4+reg.
// ---------------------------------------------------------------------------
__global__ __launch_bounds__(64) void gemm_out(
        const ushort* __restrict__ outs,   // [8192][768] bf16
        const ushort* __restrict__ lwb,    // [256][768] bf16
        const float* __restrict__ lb,
        float* __restrict__ out) {
    const int lane = threadIdx.x;
    const int m0 = blockIdx.x * 32;
    const int n0 = blockIdx.y * 32;
    const int mrow = lane & 15, quad = lane >> 4;

    f32x4 acc00 = (f32x4){0,0,0,0}, acc01 = (f32x4){0,0,0,0};
    f32x4 acc10 = (f32x4){0,0,0,0}, acc11 = (f32x4){0,0,0,0};
    const ushort* ap = outs + (size_t)(m0 + mrow) * K3 + quad * 8;
    const ushort* bp = lwb  + (size_t)(n0 + mrow) * K3 + quad * 8;

    bf16x8 A0[4], A1[4], B0[4], B1[4];
    #pragma unroll
    for (int pi = 0; pi < 3; ++pi) {
        A0[pi] = *(const bf16x8*)(ap + pi*32);
        A1[pi] = *(const bf16x8*)(ap + 16*K3 + pi*32);
        B0[pi] = *(const bf16x8*)(bp + pi*32);
        B1[pi] = *(const bf16x8*)(bp + 16*K3 + pi*32);
    }

    #pragma unroll
    for (int it = 0; it < K3/32; ++it) {
        const int sl = it & 3;
        const int nl = (it + 3) & 3;
        const int kn = (it + 3 < K3/32) ? (it + 3) * 32 : 0;   // wrap: harmless
        A0[nl] = *(const bf16x8*)(ap + kn);
        A1[nl] = *(const bf16x8*)(ap + 16*K3 + kn);
        B0[nl] = *(const bf16x8*)(bp + kn);
        B1[nl] = *(const bf16x8*)(bp + 16*K3 + kn);
        acc00 = __builtin_amdgcn_mfma_f32_16x16x32_bf16(A0[sl], B0[sl], acc00, 0, 0, 0);
        acc01 = __builtin_amdgcn_mfma_f32_16x16x32_bf16(A0[sl], B1[sl], acc01, 0, 0, 0);
        acc10 = __builtin_amdgcn_mfma_f32_16x16x32_bf16(A1[sl], B0[sl], acc10, 0, 0, 0);
        acc11 = __builtin_amdgcn_mfma_f32_16x16x32_bf16(A1[sl], B1[sl], acc11, 0, 0, 0);
    }

    #pragma unroll
    for (int i = 0; i < 2; ++i) {
        #pragma unroll
        for (int jn = 0; jn < 2; ++jn) {
            const f32x4 acc = (i==0) ? (jn==0 ? acc00 : acc01)
                                     : (jn==0 ? acc10 : acc11);
            int ncol = n0 + jn*16 + mrow;
            float lbv = lb[ncol];
            #pragma unroll
            for (int r = 0; r < 4; ++r)
                out[(size_t)(m0 + i*16 + quad*4 + r)*HH + ncol] = acc[r] + lbv;
        }
    }
}

// ---------------------------------------------------------------------------
extern "C" void kernel_launch(void* const* d_in, const int* in_sizes, int n_in,
                              void* d_out, int out_size, void* d_ws, size_t ws_size,
                              hipStream_t stream) {
    const int*   chars = (const int*)d_in[0];
    const float* emb   = (const float*)d_in[1];
    const float* w1    = (const float*)d_in[2];
    const float* b1    = (const float*)d_in[3];
    const float* w3    = (const float*)d_in[4];
    const float* b3    = (const float*)d_in[5];
    const float* w5    = (const float*)d_in[6];
    const float* b5    = (const float*)d_in[7];
    const float* lw    = (const float*)d_in[8];
    const float* lb    = (const float*)d_in[9];

    // ws: P5 [256][2304] bf16 (1.18MB) | wTp [64][2304] f32 (0.59MB)
    //   | outs [8192][768] bf16 (12.6MB) | lwb [256][768] bf16 (0.39MB)
    //   | csb [8192*20] int (0.66MB)
    ushort* P5   = (ushort*)d_ws;
    float*  wTp  = (float*)(P5 + VOCAB * UNIT);
    ushort* outs = (ushort*)(wTp + EE * UNIT);
    ushort* lwb  = outs + (size_t)NW * K3;
    int*    csb  = (int*)(lwb + (size_t)VOCAB * K3);

    prep<<<1408, 256, 0, stream>>>(chars, w1, w3, w5, lw, wTp, lwb, csb);
    build_tables<<<dim3(VOCAB/4, 9), 256, 0, stream>>>(emb, wTp, P5);
    conv_pool<<<dim3(NW/256, 32), 256, 0, stream>>>(csb, P5, b1, b3, b5, outs);
    gemm_out<<<dim3(NW/32, HH/32), 64, 0, stream>>>(outs, lwb, lb, (float*)d_out);
}